// Round 16
// baseline (991.150 us; speedup 1.0000x reference)
//
#include <hip/hip_runtime.h>
#include <hip/hip_bf16.h>
#include <math.h>

typedef unsigned short u16;
typedef unsigned int   u32;

#define CAP 48   // max neighbors per row (Binomial(511,0.02)+diag; P(>=47) ~ 1e-25)

__device__ __forceinline__ float tof(u16 u){
  union { u32 i; float f; } v; v.i = ((u32)u) << 16; return v.f;
}
__device__ __forceinline__ u16 fromf(float f){   // fp32 -> bf16 RNE
  union { float f; u32 i; } v; v.f = f;
  u32 x = v.i;
  return (u16)((x + 0x7fffu + ((x >> 16) & 1u)) >> 16);
}

// ---------------------------------------------------------------------------
// Dtype detection (1=fp32 tensors, 0=bf16 tensors). Deterministic.
// ---------------------------------------------------------------------------
__global__ void detect_dtype(const void* xp, int* flag){
  if(threadIdx.x == 0 && blockIdx.x == 0){
    const u16* p = (const u16*)xp;
    int outl = 0;
    for(int i = 0; i < 128; i++){
      u16 u = p[2*i];
      int e = (u >> 7) & 0xFF;
      if(u != 0 && (e < 100 || e > 140)) outl++;
    }
    *flag = (outl > 32) ? 1 : 0;
  }
}

// ---------------------------------------------------------------------------
// Convert all weight tensors into a contiguous fp32 arena (exact upconvert).
// ---------------------------------------------------------------------------
struct WArgs {
  const void* p[34];
  int sz[34];
  int off[35];
};

__global__ __launch_bounds__(256) void convert_weights(WArgs wa, const int* flag,
                                                       float* __restrict__ arena, int total){
  int i = blockIdx.x * 256 + threadIdx.x;
  if(i >= total) return;
  int isf = *flag;
  int t = 0;
  while(wa.off[t+1] <= i) t++;
  int j = i - wa.off[t];
  float v = 0.f;
  if(j < wa.sz[t])
    v = isf ? ((const float*)wa.p[t])[j] : tof(((const u16*)wa.p[t])[j]);
  arena[i] = v;
}

// ---------------------------------------------------------------------------
// Weight transpose (exact permutation): src[R][C] -> dst[C][R].
// ---------------------------------------------------------------------------
__global__ __launch_bounds__(256) void transpose_w(const float* __restrict__ src,
                                                   float* __restrict__ dst, int R, int C){
  int i = blockIdx.x * 256 + threadIdx.x;
  if(i < R*C){
    int r = i / C, c = i - r*C;
    dst[(size_t)c*R + r] = src[i];
  }
}

// ---------------------------------------------------------------------------
// Neighbor-list build: one wave per adjacency row, ordered ballot compaction.
// ---------------------------------------------------------------------------
__global__ __launch_bounds__(64) void build_nbr(const void* __restrict__ S,
                                                int* __restrict__ nbr_idx,
                                                int* __restrict__ nbr_cnt,
                                                const int* __restrict__ flag){
  int isf = *flag;
  int row  = blockIdx.x;              // (b*2+s)*512 + n
  int lane = threadIdx.x;
  int cnt = 0;
  for(int c = 0; c < 8; c++){
    int m = c*64 + lane;
    size_t idx = (size_t)row * 512 + m;
    float sv = isf ? ((const float*)S)[idx] : tof(((const u16*)S)[idx]);
    bool pred = fabsf(sv) > 1e-9f;
    unsigned long long mask = __ballot(pred);
    int pos = cnt + __popcll(mask & ((1ull << lane) - 1ull));
    if(pred && pos < CAP) nbr_idx[(size_t)row*CAP + pos] = m;
    cnt += __popcll(mask);
  }
  if(lane == 0) nbr_cnt[row] = cnt > CAP ? CAP : cnt;
}

// ---------------------------------------------------------------------------
// Encoder convs (fp32, np-association): conv0+relu, conv1+relu, +residual.
// R13 version: padded 18x18 LDS images (stride-18). NOTE: SQ_LDS_BANK_CONFLICT
// ~1.245e7 here is the free 2-way wave64/32-bank baseline (R15 A/B test:
// identical count at stride 24 while dur regressed on occupancy) — not a
// real stall source. 25 KB LDS -> ~6 blocks/CU.
// ---------------------------------------------------------------------------
__global__ __launch_bounds__(256) void encoder_conv(
    const void* __restrict__ x, const int* __restrict__ flag,
    const float* __restrict__ w0, const float* __restrict__ b0,
    const float* __restrict__ w1, const float* __restrict__ b1,
    float* __restrict__ e1n)
{
  __shared__ float xpad[3][18][18];
  __shared__ float e0p[16][18][18];

  int isf = *flag;
  int tid = threadIdx.x;
  size_t img = blockIdx.x;
  int py = tid >> 4, px = tid & 15;

  float* z1 = &xpad[0][0][0];
  for(int i = tid; i < 972; i += 256) z1[i] = 0.f;
  float* z2 = &e0p[0][0][0];
  for(int i = tid; i < 5184; i += 256) z2[i] = 0.f;
  __syncthreads();

  #pragma unroll
  for(int i = 0; i < 3; i++){
    size_t gi = img*768 + i*256 + tid;
    xpad[i][1+py][1+px] = isf ? ((const float*)x)[gi] : tof(((const u16*)x)[gi]);
  }
  __syncthreads();

  float acc1[3] = {0.f, 0.f, 0.f};

  for(int grp = 0; grp < 2; grp++){
    float acc0[16];
    #pragma unroll
    for(int o = 0; o < 16; o++) acc0[o] = 0.f;
    for(int i = 0; i < 3; i++){
      float rr[9];
      #pragma unroll
      for(int ky = 0; ky < 3; ky++)
        #pragma unroll
        for(int kx = 0; kx < 3; kx++)
          rr[ky*3+kx] = xpad[i][py+ky][px+kx];
      #pragma unroll
      for(int o = 0; o < 16; o++){
        #pragma unroll
        for(int t = 0; t < 9; t++)
          acc0[o] = fmaf(rr[t], w0[(grp*16+o)*27 + i*9 + t], acc0[o]);
      }
    }
    __syncthreads();
    #pragma unroll
    for(int o = 0; o < 16; o++)
      e0p[o][1+py][1+px] = fmaxf(acc0[o] + b0[grp*16 + o], 0.f);
    __syncthreads();

    for(int i = 0; i < 16; i++){
      float rr[9];
      #pragma unroll
      for(int ky = 0; ky < 3; ky++)
        #pragma unroll
        for(int kx = 0; kx < 3; kx++)
          rr[ky*3+kx] = e0p[i][py+ky][px+kx];
      int ic = grp*16 + i;
      #pragma unroll
      for(int o = 0; o < 3; o++){
        #pragma unroll
        for(int t = 0; t < 9; t++)
          acc1[o] = fmaf(rr[t], w1[o*288 + ic*9 + t], acc1[o]);
      }
    }
  }

  #pragma unroll
  for(int o = 0; o < 3; o++)
    e1n[img*768 + o*256 + tid] = fmaxf(acc1[o] + b1[o], 0.f) + xpad[o][1+py][1+px];
}

// ---------------------------------------------------------------------------
// flat GEMM: g_f[img][j] = relu( sum_{i<768} e1[img][i]*fwT[i][j] + fb[j] ).
// Tile 64m x 64n x 16k, padded LDS (stride 68: B-transpose staging writes
// were 4-way at stride 64). grid (64, 2).
// ---------------------------------------------------------------------------
__global__ __launch_bounds__(256) void gemm_flat(
    const float* __restrict__ e1n, const float* __restrict__ fwT,
    const float* __restrict__ fb, float* __restrict__ g)
{
  __shared__ float As[16][68];
  __shared__ float Bs[16][68];
  int tid = threadIdx.x;
  int n0 = blockIdx.x * 64, m0 = blockIdx.y * 64;

  int lk = tid >> 4;
  int l4 = (tid & 15) * 4;
  int br = tid >> 2;          // 0..63  (img within tile)
  int bc = (tid & 3) * 4;     // 0,4,8,12 (k within chunk)

  float acc[4][4];
  #pragma unroll
  for(int i = 0; i < 4; i++)
    #pragma unroll
    for(int jj = 0; jj < 4; jj++) acc[i][jj] = 0.f;

  int tm = tid >> 4, tn = tid & 15;
  for(int kt = 0; kt < 48; kt++){
    int k0 = kt*16;
    *(float4*)&As[lk][l4] = *(const float4*)&fwT[(size_t)(k0 + lk)*128 + m0 + l4];
    float4 bv = *(const float4*)&e1n[(size_t)(n0 + br)*768 + k0 + bc];
    Bs[bc+0][br] = bv.x; Bs[bc+1][br] = bv.y; Bs[bc+2][br] = bv.z; Bs[bc+3][br] = bv.w;
    __syncthreads();
    #pragma unroll
    for(int kk = 0; kk < 16; kk++){
      float4 a  = *(const float4*)&As[kk][tm*4];
      float4 xx = *(const float4*)&Bs[kk][tn*4];
      float av[4]  = {a.x, a.y, a.z, a.w};
      float xvv[4] = {xx.x, xx.y, xx.z, xx.w};
      #pragma unroll
      for(int i = 0; i < 4; i++)
        #pragma unroll
        for(int jj = 0; jj < 4; jj++)
          acc[i][jj] = fmaf(av[i], xvv[jj], acc[i][jj]);
    }
    __syncthreads();
  }

  #pragma unroll
  for(int jj = 0; jj < 4; jj++){
    int img = n0 + tn*4 + jj;
    float4 r = make_float4(fmaxf(acc[0][jj] + fb[m0+tm*4+0], 0.f),
                           fmaxf(acc[1][jj] + fb[m0+tm*4+1], 0.f),
                           fmaxf(acc[2][jj] + fb[m0+tm*4+2], 0.f),
                           fmaxf(acc[3][jj] + fb[m0+tm*4+3], 0.f));
    *(float4*)&g[(size_t)img*128 + m0 + tm*4] = r;
  }
}

// ---------------------------------------------------------------------------
// key/qry GEMM 64m x 64n x 32k with transposed output kqT[bp][n][2F].
// Padded LDS (68 stride). grid: (8 n-tiles, 2F/64, 32 bp).
// ---------------------------------------------------------------------------
__global__ __launch_bounds__(256) void gemm_kq(
    const float* __restrict__ X,
    const float* __restrict__ wk, const float* __restrict__ wq,
    float* __restrict__ kqT, int G, int F)
{
  __shared__ float Ws[32][68];
  __shared__ float Xs[32][68];
  int tid = threadIdx.x;
  int bp = blockIdx.z;
  int b = bp >> 2, p = bp & 3;
  int n0 = blockIdx.x * 64, m0 = blockIdx.y * 64;
  const float* Xb = X + (size_t)b * G * 512;

  int lk = tid >> 4;          // 0..15
  int l4 = (tid & 15) * 4;

  int mg = m0 + l4;
  int quad = mg / F;
  int mq = mg - quad * F;
  size_t GF = (size_t)G * F;
  const float* wb = (quad == 0 ? wk : wq) + (size_t)p * GF + mq;

  float acc[4][4];
  #pragma unroll
  for(int i = 0; i < 4; i++)
    #pragma unroll
    for(int jj = 0; jj < 4; jj++) acc[i][jj] = 0.f;

  int tm = tid >> 4, tn = tid & 15;
  int KT = G / 32;
  for(int kt = 0; kt < KT; kt++){
    int k = kt*32 + lk;
    *(float4*)&Ws[lk][l4]      = *(const float4*)(wb + (size_t)k * F);
    *(float4*)&Ws[lk+16][l4]   = *(const float4*)(wb + (size_t)(k+16) * F);
    *(float4*)&Xs[lk][l4]      = *(const float4*)(Xb + (size_t)k * 512 + n0 + l4);
    *(float4*)&Xs[lk+16][l4]   = *(const float4*)(Xb + (size_t)(k+16) * 512 + n0 + l4);
    __syncthreads();
    #pragma unroll
    for(int kk = 0; kk < 32; kk++){
      float4 a  = *(const float4*)&Ws[kk][tm*4];
      float4 xx = *(const float4*)&Xs[kk][tn*4];
      float av[4]  = {a.x, a.y, a.z, a.w};
      float xvv[4] = {xx.x, xx.y, xx.z, xx.w};
      #pragma unroll
      for(int i = 0; i < 4; i++)
        #pragma unroll
        for(int jj = 0; jj < 4; jj++)
          acc[i][jj] = fmaf(av[i], xvv[jj], acc[i][jj]);
    }
    __syncthreads();
  }

  int F2 = 2*F;
  float* ob = kqT + (size_t)bp * 512 * F2;
  #pragma unroll
  for(int jj = 0; jj < 4; jj++){
    float* orow = ob + (size_t)(n0 + tn*4 + jj) * F2 + m0 + tm*4;
    #pragma unroll
    for(int i = 0; i < 4; i++) orow[i] = acc[i][jj];
  }
}

// ---------------------------------------------------------------------------
// Sparse scores + masked softmax. 4 waves/block, wave = one (bp,n) row.
// kqT: [bp][n][2F]. Ascending-f chain; lane-0 sequential reductions.
// grid: 4096 x 256.
// ---------------------------------------------------------------------------
__global__ __launch_bounds__(256) void attn_sparse(
    const float* __restrict__ kqT,
    const int* __restrict__ nbr_idx, const int* __restrict__ nbr_cnt,
    float* __restrict__ aijv, int F, int s)
{
  __shared__ float qs[4][128];
  __shared__ float sc[4][64];
  __shared__ float ev[4][64];
  __shared__ float red[4][2];
  int w = threadIdx.x >> 6;
  int lane = threadIdx.x & 63;
  int rid = blockIdx.x * 4 + w;         // bp*512 + n
  int n = rid & 511;
  int bp = rid >> 9;
  int b = bp >> 2;
  int F2 = 2*F;
  const float* qrow = kqT + ((size_t)bp * 512 + n) * F2 + F;   // qry half
  if(lane < F/4) *(float4*)&qs[w][lane*4] = *(const float4*)&qrow[lane*4];
  __syncthreads();

  int srow = (b*2 + s)*512 + n;
  int cnt = nbr_cnt[srow];
  const int* il = nbr_idx + (size_t)srow * CAP;

  float sval = 0.f;
  if(lane < cnt){
    int m = il[lane];
    const float* krow = kqT + ((size_t)bp * 512 + m) * F2;     // key half
    float a = 0.f;
    for(int f = 0; f < F; f += 4){
      float4 k4 = *(const float4*)&krow[f];
      a = fmaf(qs[w][f],   k4.x, a);
      a = fmaf(qs[w][f+1], k4.y, a);
      a = fmaf(qs[w][f+2], k4.z, a);
      a = fmaf(qs[w][f+3], k4.w, a);
    }
    sval = a >= 0.f ? a : 0.2f * a;     // leaky_relu slope 0.2
  }
  sc[w][lane] = sval;
  __syncthreads();
  if(lane == 0){
    float mx = -1e30f;
    for(int j = 0; j < cnt; j++) mx = fmaxf(mx, sc[w][j]);
    red[w][0] = mx;
  }
  __syncthreads();
  float e = (lane < cnt) ? expf(sval - red[w][0]) : 0.f;
  ev[w][lane] = e;
  __syncthreads();
  if(lane == 0){
    float ssum = 0.f;
    for(int j = 0; j < cnt; j++) ssum += ev[w][j];
    red[w][1] = ssum;
  }
  __syncthreads();
  if(lane < cnt) aijv[(size_t)rid * CAP + lane] = e / red[w][1];
}

// ---------------------------------------------------------------------------
// Xp[bp][g][n] = sum_j aij[n,j] x[b,g,il[n,j]] (ascending j == np order).
// Grid (8 n-tiles, G/32 g-blocks, 32 bp).
// ---------------------------------------------------------------------------
__global__ __launch_bounds__(256) void fill_Xp(
    const float* __restrict__ X, const float* __restrict__ aijv,
    const int* __restrict__ nbr_idx, const int* __restrict__ nbr_cnt,
    float* __restrict__ Xp, int G, int s)
{
  __shared__ float xrows[8][512];
  __shared__ float av_s[64][CAP+1];
  __shared__ u16   il_s[64][CAP+2];
  __shared__ int   cnt_s[64];

  int tid = threadIdx.x;
  int n0 = blockIdx.x * 64;
  int g0 = blockIdx.y * 32;
  int bp = blockIdx.z;
  int b = bp >> 2;
  int srow0 = (b*2 + s)*512 + n0;

  for(int i = tid; i < 64*CAP; i += 256){
    int r = i / CAP, j = i - r*CAP;
    il_s[r][j] = (u16)nbr_idx[(size_t)(srow0 + r)*CAP + j];
    av_s[r][j] = aijv[((size_t)bp*512 + n0 + r)*CAP + j];
  }
  if(tid < 64) cnt_s[tid] = nbr_cnt[srow0 + tid];

  int n_l = tid & 63;
  int gs  = tid >> 6;
  const float* Xb  = X  + ((size_t)b  * G + g0) * 512;
  float*       XpB = Xp + ((size_t)bp * G + g0) * 512;

  for(int gb = 0; gb < 32; gb += 8){
    __syncthreads();
    for(int i = tid; i < 8*128; i += 256){
      int gr = i >> 7, c4 = (i & 127) * 4;
      *(float4*)&xrows[gr][c4] = *(const float4*)&Xb[(size_t)(gb + gr)*512 + c4];
    }
    __syncthreads();
    int cnt = cnt_s[n_l];
    float a0 = 0.f, a1 = 0.f;
    for(int j = 0; j < cnt; j++){
      float w = av_s[n_l][j];
      int   m = il_s[n_l][j];
      a0 = fmaf(w, xrows[gs][m],     a0);
      a1 = fmaf(w, xrows[gs + 4][m], a1);
    }
    XpB[(size_t)(gb + gs)*512     + n0 + n_l] = a0;
    XpB[(size_t)(gb + gs + 4)*512 + n0 + n_l] = a1;
  }
}

// ---------------------------------------------------------------------------
// Output GEMM 64m x 64n x 32k: y[f,n] = sum_c src(c)[n]*wf[..]; src: X | Xp.
// Padded LDS. Ascending-c chain; +bias, relu, store/accumulate.
// grid (8, ceil(F/64), 32 bp).
// ---------------------------------------------------------------------------
__global__ __launch_bounds__(256) void gemm_y(
    const float* __restrict__ X, const float* __restrict__ Xp,
    const float* __restrict__ wf, const float* __restrict__ bias,
    float* __restrict__ out, int G, int F, int PFout, int accmode)
{
  __shared__ float Ws[32][68];
  __shared__ float Xs[32][68];
  int tid = threadIdx.x;
  int bp = blockIdx.z;
  int b = bp >> 2, p = bp & 3;
  int n0 = blockIdx.x * 64, m0 = blockIdx.y * 64;

  int lk = tid >> 4;
  int l4 = (tid & 15) * 4;
  int mg = m0 + l4;
  int fcl = mg < F ? mg : (F - 4);
  size_t GF2 = (size_t)2 * G * F;
  const float* wb = wf + (size_t)p * GF2 + fcl;

  float acc[4][4];
  #pragma unroll
  for(int i = 0; i < 4; i++)
    #pragma unroll
    for(int jj = 0; jj < 4; jj++) acc[i][jj] = 0.f;

  int tm = tid >> 4, tn = tid & 15;
  int KT = (2*G) / 32;
  for(int kt = 0; kt < KT; kt++){
    int c0 = kt*32 + lk;
    int c1 = c0 + 16;
    const float* xr0 = (c0 < G) ? (X  + ((size_t)b  * G + c0      ) * 512)
                                : (Xp + ((size_t)bp * G + (c0 - G)) * 512);
    const float* xr1 = (c1 < G) ? (X  + ((size_t)b  * G + c1      ) * 512)
                                : (Xp + ((size_t)bp * G + (c1 - G)) * 512);
    *(float4*)&Ws[lk][l4]    = *(const float4*)(wb + (size_t)c0 * F);
    *(float4*)&Ws[lk+16][l4] = *(const float4*)(wb + (size_t)c1 * F);
    *(float4*)&Xs[lk][l4]    = *(const float4*)(xr0 + n0 + l4);
    *(float4*)&Xs[lk+16][l4] = *(const float4*)(xr1 + n0 + l4);
    __syncthreads();
    #pragma unroll
    for(int kk = 0; kk < 32; kk++){
      float4 a  = *(const float4*)&Ws[kk][tm*4];
      float4 xx = *(const float4*)&Xs[kk][tn*4];
      float av[4]  = {a.x, a.y, a.z, a.w};
      float xvv[4] = {xx.x, xx.y, xx.z, xx.w};
      #pragma unroll
      for(int i = 0; i < 4; i++)
        #pragma unroll
        for(int jj = 0; jj < 4; jj++)
          acc[i][jj] = fmaf(av[i], xvv[jj], acc[i][jj]);
    }
    __syncthreads();
  }

  int mrow = m0 + tm*4;
  if(mrow < F){
    float* ob = out + ((size_t)b * PFout + (size_t)p * F + mrow) * 512 + n0 + tn*4;
    #pragma unroll
    for(int i = 0; i < 4; i++){
      float bv = bias[mrow + i];
      float4 r = make_float4(fmaxf(acc[i][0] + bv, 0.f),
                             fmaxf(acc[i][1] + bv, 0.f),
                             fmaxf(acc[i][2] + bv, 0.f),
                             fmaxf(acc[i][3] + bv, 0.f));
      float* dst = ob + (size_t)i * 512;
      if(accmode){
        float4 old = *(float4*)dst;
        r.x += old.x; r.y += old.y; r.z += old.z; r.w += old.w;
      }
      *(float4*)dst = r;
    }
  }
}

// ---------------------------------------------------------------------------
// dec0 GEMM: d[row][m] = relu( sum_{c<512} u1flat[row][c]*dw0T[c][m] + b0[m] );
// u1flat row r is contiguous memory at u1 + r*512. Tile 64x64x16, padded LDS.
// grid (64, 4).
// ---------------------------------------------------------------------------
__global__ __launch_bounds__(256) void gemm_dec0(
    const float* __restrict__ u1, const float* __restrict__ w0T,
    const float* __restrict__ b0, float* __restrict__ d)
{
  __shared__ float As[16][68];
  __shared__ float Bs[16][68];
  int tid = threadIdx.x;
  int n0 = blockIdx.x * 64;
  int m0 = blockIdx.y * 64;

  int lk = tid >> 4;
  int l4 = (tid & 15) * 4;
  int br = tid >> 2;
  int bc = (tid & 3) * 4;

  float acc[4][4];
  #pragma unroll
  for(int i = 0; i < 4; i++)
    #pragma unroll
    for(int jj = 0; jj < 4; jj++) acc[i][jj] = 0.f;

  int tm = tid >> 4, tn = tid & 15;
  for(int kt = 0; kt < 32; kt++){
    int k0 = kt*16;
    *(float4*)&As[lk][l4] = *(const float4*)&w0T[(size_t)(k0 + lk)*256 + m0 + l4];
    float4 bv = *(const float4*)&u1[(size_t)(n0 + br)*512 + k0 + bc];
    Bs[bc+0][br] = bv.x; Bs[bc+1][br] = bv.y; Bs[bc+2][br] = bv.z; Bs[bc+3][br] = bv.w;
    __syncthreads();
    #pragma unroll
    for(int kk = 0; kk < 16; kk++){
      float4 a  = *(const float4*)&As[kk][tm*4];
      float4 xx = *(const float4*)&Bs[kk][tn*4];
      float av[4]  = {a.x, a.y, a.z, a.w};
      float xvv[4] = {xx.x, xx.y, xx.z, xx.w};
      #pragma unroll
      for(int i = 0; i < 4; i++)
        #pragma unroll
        for(int jj = 0; jj < 4; jj++)
          acc[i][jj] = fmaf(av[i], xvv[jj], acc[i][jj]);
    }
    __syncthreads();
  }

  #pragma unroll
  for(int jj = 0; jj < 4; jj++){
    int row = n0 + tn*4 + jj;
    float4 r = make_float4(fmaxf(acc[0][jj] + b0[m0+tm*4+0], 0.f),
                           fmaxf(acc[1][jj] + b0[m0+tm*4+1], 0.f),
                           fmaxf(acc[2][jj] + b0[m0+tm*4+2], 0.f),
                           fmaxf(acc[3][jj] + b0[m0+tm*4+3], 0.f));
    *(float4*)&d[(size_t)row*256 + m0 + tm*4] = r;
  }
}

// ---------------------------------------------------------------------------
// Decoder stage 2: one wave per row; 5 sequential np-order dots + softmax.
// ---------------------------------------------------------------------------
__global__ __launch_bounds__(64) void decoder2(
    const float* __restrict__ d,
    const float* __restrict__ w1, const float* __restrict__ b1,
    const int* __restrict__ flag, void* __restrict__ outp)
{
  __shared__ float ds[256];
  __shared__ float lg[5];
  int r = blockIdx.x, lane = threadIdx.x;
  for(int i = lane; i < 256; i += 64) ds[i] = d[(size_t)r*256 + i];
  __syncthreads();

  if(lane < 5){
    float a = 0.f;
    const float* wr = w1 + (size_t)lane * 256;
    for(int i = 0; i < 256; i++) a = fmaf(ds[i], wr[i], a);
    lg[lane] = a + b1[lane];
  }
  __syncthreads();
  if(lane < 5){
    float mx = lg[0];
    for(int i = 1; i < 5; i++) mx = fmaxf(mx, lg[i]);
    float ssum = 0.f;
    for(int i = 0; i < 5; i++) ssum += expf(lg[i] - mx);
    float v = expf(lg[lane] - mx) / ssum;
    if(*flag) ((float*)outp)[(size_t)r*5 + lane] = v;
    else      ((u16*)outp)[(size_t)r*5 + lane] = fromf(v);
  }
}

// ---------------------------------------------------------------------------
extern "C" void kernel_launch(void* const* d_in, const int* in_sizes, int n_in,
                              void* d_out, int out_size, void* d_ws, size_t ws_size,
                              hipStream_t stream)
{
  (void)n_in; (void)out_size; (void)ws_size;
  const void* x = d_in[0];
  const void* S = d_in[1];

  float* wsf   = (float*)d_ws;
  int*   flag  = (int*)d_ws;          // word 0
  float* arena = wsf + 1024;

  WArgs wa;
  long long aoff[35]; aoff[0] = 0;
  for(int t = 0; t < 34; t++){
    wa.p[t]  = d_in[2 + t];
    wa.sz[t] = in_sizes[2 + t];
    wa.off[t] = (int)aoff[t];
    aoff[t+1] = aoff[t] + ((in_sizes[2 + t] + 15) & ~15);
  }
  wa.off[34] = (int)aoff[34];
  int total = (int)aoff[34];

  size_t cur = 1024 + (size_t)((total + 1023) & ~1023);
  float* g    = wsf + cur; cur += 524288;                 // (B,128,512) flat
  float* p1   = wsf + cur; cur += 2097152;                // (B,512,512)
  float* p2   = wsf + cur; cur += 524288;                 // (B,128,512)
  float* u0b  = wsf + cur; cur += 1048576;                // (B,256,512)
  float* u1b  = p1;                                       // reuse (p1 dead after L3 reads)
  float* scr  = wsf + cur; cur += (size_t)32*512*512;     // e1 / kqT / Xp / d union
  float* aijv = wsf + cur; cur += (size_t)32*512*CAP;     // (32, 512, CAP)
  float* fwT  = wsf + cur; cur += 98304;                  // (768,128)
  float* dw0T = wsf + cur; cur += 131072;                 // (512,256)
  int*   ncnt = (int*)(wsf + cur); cur += 8192;
  int*   nidx = (int*)(wsf + cur); cur += (size_t)8192 * CAP;

  float* e1n = scr;   // [4096][768]   — dead after gemm_flat
  float* kqT = scr;   // [32][512][2F] — dead after attn_sparse
  float* Xp  = scr;   // [32][G][512]  — written after attn_sparse
  float* dbuf= scr;   // [4096][256]   — after layers

  const float* A[34];
  for(int t = 0; t < 34; t++) A[t] = arena + aoff[t];
  const float* c0w = A[0], *c0b = A[1], *c1w = A[2], *c1b = A[3];
  const float* fw  = A[4], *fb  = A[5];
  const float *wk_[6], *wq_[6], *wf_[6], *bias_[6];
  for(int l = 0; l < 6; l++){
    wk_[l]   = A[6 + 4*l];
    wq_[l]   = A[7 + 4*l];
    wf_[l]   = A[8 + 4*l];
    bias_[l] = A[9 + 4*l];
  }
  const float* dw0 = A[30], *db0 = A[31], *dw1 = A[32], *db1 = A[33];

  detect_dtype<<<1, 64, 0, stream>>>(x, flag);
  convert_weights<<<(total + 255)/256, 256, 0, stream>>>(wa, flag, arena, total);
  transpose_w<<<(98304 + 255)/256, 256, 0, stream>>>(fw, fwT, 128, 768);
  transpose_w<<<(131072 + 255)/256, 256, 0, stream>>>(dw0, dw0T, 256, 512);
  build_nbr<<<8192, 64, 0, stream>>>(S, nidx, ncnt, flag);
  encoder_conv<<<4096, 256, 0, stream>>>(x, flag, c0w, c0b, c1w, c1b, e1n);
  gemm_flat<<<dim3(64, 2), 256, 0, stream>>>(e1n, fwT, fb, g);

  struct Lyr { int G, F, s; const float* in; float* out; int PF; int acc; int w; };
  const Lyr Ls[6] = {
    {128, 128, 0, g,   p1,  512, 0, 0},  // p1 = gat(g, S0, d0)
    {512,  32, 1, p1,  p2,  128, 0, 1},  // p2 = gat(p1, S1, d1)
    {128,  64, 1, p2,  u0b, 256, 0, 2},  // u0  = gat(p2, S1, u0)
    {512,  64, 1, p1,  u0b, 256, 1, 5},  //     + gat(p1, S1, s1)
    {256, 128, 0, u0b, u1b, 512, 0, 3},  // u1  = gat(u0, S0, u1)
    {128, 128, 0, g,   u1b, 512, 1, 4},  //     + gat(g,  S0, s0)
  };
  for(int i = 0; i < 6; i++){
    const Lyr& L = Ls[i];
    dim3 gk(8, (2*L.F)/64 > 0 ? (2*L.F)/64 : 1, 32);
    gemm_kq<<<gk, 256, 0, stream>>>(L.in, wk_[L.w], wq_[L.w], kqT, L.G, L.F);
    attn_sparse<<<4096, 256, 0, stream>>>(kqT, nidx, ncnt, aijv, L.F, L.s);
    fill_Xp<<<dim3(8, L.G/32, 32), 256, 0, stream>>>(L.in, aijv, nidx, ncnt, Xp, L.G, L.s);
    dim3 gy(8, (L.F + 63)/64, 32);
    gemm_y<<<gy, 256, 0, stream>>>(L.in, Xp, wf_[L.w], bias_[L.w], L.out,
                                   L.G, L.F, L.PF, L.acc);
  }

  gemm_dec0<<<dim3(64, 4), 256, 0, stream>>>(u1b, dw0T, db0, dbuf);
  decoder2<<<4096, 64, 0, stream>>>(dbuf, dw1, db1, flag, d_out);
}

// Round 17
// 980.818 us; speedup vs baseline: 1.0105x; 1.0105x over previous
//
#include <hip/hip_runtime.h>
#include <hip/hip_bf16.h>
#include <math.h>

typedef unsigned short u16;
typedef unsigned int   u32;

#define CAP 48   // max neighbors per row (Binomial(511,0.02)+diag; P(>=47) ~ 1e-25)

__device__ __forceinline__ float tof(u16 u){
  union { u32 i; float f; } v; v.i = ((u32)u) << 16; return v.f;
}
__device__ __forceinline__ u16 fromf(float f){   // fp32 -> bf16 RNE
  union { float f; u32 i; } v; v.f = f;
  u32 x = v.i;
  return (u16)((x + 0x7fffu + ((x >> 16) & 1u)) >> 16);
}

// ---------------------------------------------------------------------------
// Dtype detection (1=fp32 tensors, 0=bf16 tensors). Deterministic.
// ---------------------------------------------------------------------------
__global__ void detect_dtype(const void* xp, int* flag){
  if(threadIdx.x == 0 && blockIdx.x == 0){
    const u16* p = (const u16*)xp;
    int outl = 0;
    for(int i = 0; i < 128; i++){
      u16 u = p[2*i];
      int e = (u >> 7) & 0xFF;
      if(u != 0 && (e < 100 || e > 140)) outl++;
    }
    *flag = (outl > 32) ? 1 : 0;
  }
}

// ---------------------------------------------------------------------------
// Convert all weight tensors into a contiguous fp32 arena (exact upconvert).
// ---------------------------------------------------------------------------
struct WArgs {
  const void* p[34];
  int sz[34];
  int off[35];
};

__global__ __launch_bounds__(256) void convert_weights(WArgs wa, const int* flag,
                                                       float* __restrict__ arena, int total){
  int i = blockIdx.x * 256 + threadIdx.x;
  if(i >= total) return;
  int isf = *flag;
  int t = 0;
  while(wa.off[t+1] <= i) t++;
  int j = i - wa.off[t];
  float v = 0.f;
  if(j < wa.sz[t])
    v = isf ? ((const float*)wa.p[t])[j] : tof(((const u16*)wa.p[t])[j]);
  arena[i] = v;
}

// ---------------------------------------------------------------------------
// Weight transpose (exact permutation): src[R][C] -> dst[C][R].
// ---------------------------------------------------------------------------
__global__ __launch_bounds__(256) void transpose_w(const float* __restrict__ src,
                                                   float* __restrict__ dst, int R, int C){
  int i = blockIdx.x * 256 + threadIdx.x;
  if(i < R*C){
    int r = i / C, c = i - r*C;
    dst[(size_t)c*R + r] = src[i];
  }
}

// ---------------------------------------------------------------------------
// Neighbor-list build: one wave per adjacency row, ordered ballot compaction.
// ---------------------------------------------------------------------------
__global__ __launch_bounds__(64) void build_nbr(const void* __restrict__ S,
                                                int* __restrict__ nbr_idx,
                                                int* __restrict__ nbr_cnt,
                                                const int* __restrict__ flag){
  int isf = *flag;
  int row  = blockIdx.x;              // (b*2+s)*512 + n
  int lane = threadIdx.x;
  int cnt = 0;
  for(int c = 0; c < 8; c++){
    int m = c*64 + lane;
    size_t idx = (size_t)row * 512 + m;
    float sv = isf ? ((const float*)S)[idx] : tof(((const u16*)S)[idx]);
    bool pred = fabsf(sv) > 1e-9f;
    unsigned long long mask = __ballot(pred);
    int pos = cnt + __popcll(mask & ((1ull << lane) - 1ull));
    if(pred && pos < CAP) nbr_idx[(size_t)row*CAP + pos] = m;
    cnt += __popcll(mask);
  }
  if(lane == 0) nbr_cnt[row] = cnt > CAP ? CAP : cnt;
}

// ---------------------------------------------------------------------------
// Encoder convs (fp32, np-association): conv0+relu, conv1+relu, +residual.
// R13 version (proven 77 us). SQ_LDS_BANK_CONFLICT ~1.245e7 here is the free
// 2-way wave64/32-bank baseline (R15 A/B test) — not a stall source.
// ---------------------------------------------------------------------------
__global__ __launch_bounds__(256) void encoder_conv(
    const void* __restrict__ x, const int* __restrict__ flag,
    const float* __restrict__ w0, const float* __restrict__ b0,
    const float* __restrict__ w1, const float* __restrict__ b1,
    float* __restrict__ e1n)
{
  __shared__ float xpad[3][18][18];
  __shared__ float e0p[16][18][18];

  int isf = *flag;
  int tid = threadIdx.x;
  size_t img = blockIdx.x;
  int py = tid >> 4, px = tid & 15;

  float* z1 = &xpad[0][0][0];
  for(int i = tid; i < 972; i += 256) z1[i] = 0.f;
  float* z2 = &e0p[0][0][0];
  for(int i = tid; i < 5184; i += 256) z2[i] = 0.f;
  __syncthreads();

  #pragma unroll
  for(int i = 0; i < 3; i++){
    size_t gi = img*768 + i*256 + tid;
    xpad[i][1+py][1+px] = isf ? ((const float*)x)[gi] : tof(((const u16*)x)[gi]);
  }
  __syncthreads();

  float acc1[3] = {0.f, 0.f, 0.f};

  for(int grp = 0; grp < 2; grp++){
    float acc0[16];
    #pragma unroll
    for(int o = 0; o < 16; o++) acc0[o] = 0.f;
    for(int i = 0; i < 3; i++){
      float rr[9];
      #pragma unroll
      for(int ky = 0; ky < 3; ky++)
        #pragma unroll
        for(int kx = 0; kx < 3; kx++)
          rr[ky*3+kx] = xpad[i][py+ky][px+kx];
      #pragma unroll
      for(int o = 0; o < 16; o++){
        #pragma unroll
        for(int t = 0; t < 9; t++)
          acc0[o] = fmaf(rr[t], w0[(grp*16+o)*27 + i*9 + t], acc0[o]);
      }
    }
    __syncthreads();
    #pragma unroll
    for(int o = 0; o < 16; o++)
      e0p[o][1+py][1+px] = fmaxf(acc0[o] + b0[grp*16 + o], 0.f);
    __syncthreads();

    for(int i = 0; i < 16; i++){
      float rr[9];
      #pragma unroll
      for(int ky = 0; ky < 3; ky++)
        #pragma unroll
        for(int kx = 0; kx < 3; kx++)
          rr[ky*3+kx] = e0p[i][py+ky][px+kx];
      int ic = grp*16 + i;
      #pragma unroll
      for(int o = 0; o < 3; o++){
        #pragma unroll
        for(int t = 0; t < 9; t++)
          acc1[o] = fmaf(rr[t], w1[o*288 + ic*9 + t], acc1[o]);
      }
    }
  }

  #pragma unroll
  for(int o = 0; o < 3; o++)
    e1n[img*768 + o*256 + tid] = fmaxf(acc1[o] + b1[o], 0.f) + xpad[o][1+py][1+px];
}

// ---------------------------------------------------------------------------
// flat GEMM: g_f[img][j] = relu( sum_{i<768} e1[img][i]*fwT[i][j] + fb[j] ).
// Tile 64m x 64n x 16k, padded LDS. grid (64, 2).
// ---------------------------------------------------------------------------
__global__ __launch_bounds__(256) void gemm_flat(
    const float* __restrict__ e1n, const float* __restrict__ fwT,
    const float* __restrict__ fb, float* __restrict__ g)
{
  __shared__ float As[16][68];
  __shared__ float Bs[16][68];
  int tid = threadIdx.x;
  int n0 = blockIdx.x * 64, m0 = blockIdx.y * 64;

  int lk = tid >> 4;
  int l4 = (tid & 15) * 4;
  int br = tid >> 2;          // 0..63  (img within tile)
  int bc = (tid & 3) * 4;     // 0,4,8,12 (k within chunk)

  float acc[4][4];
  #pragma unroll
  for(int i = 0; i < 4; i++)
    #pragma unroll
    for(int jj = 0; jj < 4; jj++) acc[i][jj] = 0.f;

  int tm = tid >> 4, tn = tid & 15;
  for(int kt = 0; kt < 48; kt++){
    int k0 = kt*16;
    *(float4*)&As[lk][l4] = *(const float4*)&fwT[(size_t)(k0 + lk)*128 + m0 + l4];
    float4 bv = *(const float4*)&e1n[(size_t)(n0 + br)*768 + k0 + bc];
    Bs[bc+0][br] = bv.x; Bs[bc+1][br] = bv.y; Bs[bc+2][br] = bv.z; Bs[bc+3][br] = bv.w;
    __syncthreads();
    #pragma unroll
    for(int kk = 0; kk < 16; kk++){
      float4 a  = *(const float4*)&As[kk][tm*4];
      float4 xx = *(const float4*)&Bs[kk][tn*4];
      float av[4]  = {a.x, a.y, a.z, a.w};
      float xvv[4] = {xx.x, xx.y, xx.z, xx.w};
      #pragma unroll
      for(int i = 0; i < 4; i++)
        #pragma unroll
        for(int jj = 0; jj < 4; jj++)
          acc[i][jj] = fmaf(av[i], xvv[jj], acc[i][jj]);
    }
    __syncthreads();
  }

  #pragma unroll
  for(int jj = 0; jj < 4; jj++){
    int img = n0 + tn*4 + jj;
    float4 r = make_float4(fmaxf(acc[0][jj] + fb[m0+tm*4+0], 0.f),
                           fmaxf(acc[1][jj] + fb[m0+tm*4+1], 0.f),
                           fmaxf(acc[2][jj] + fb[m0+tm*4+2], 0.f),
                           fmaxf(acc[3][jj] + fb[m0+tm*4+3], 0.f));
    *(float4*)&g[(size_t)img*128 + m0 + tm*4] = r;
  }
}

// ---------------------------------------------------------------------------
// key/qry GEMM 64m x 64n x 32k with transposed output kqT[bp][n][2F].
// Padded LDS. grid: (8 n-tiles, 2F/64, 32 bp).
// ---------------------------------------------------------------------------
__global__ __launch_bounds__(256) void gemm_kq(
    const float* __restrict__ X,
    const float* __restrict__ wk, const float* __restrict__ wq,
    float* __restrict__ kqT, int G, int F)
{
  __shared__ float Ws[32][68];
  __shared__ float Xs[32][68];
  int tid = threadIdx.x;
  int bp = blockIdx.z;
  int b = bp >> 2, p = bp & 3;
  int n0 = blockIdx.x * 64, m0 = blockIdx.y * 64;
  const float* Xb = X + (size_t)b * G * 512;

  int lk = tid >> 4;          // 0..15
  int l4 = (tid & 15) * 4;

  int mg = m0 + l4;
  int quad = mg / F;
  int mq = mg - quad * F;
  size_t GF = (size_t)G * F;
  const float* wb = (quad == 0 ? wk : wq) + (size_t)p * GF + mq;

  float acc[4][4];
  #pragma unroll
  for(int i = 0; i < 4; i++)
    #pragma unroll
    for(int jj = 0; jj < 4; jj++) acc[i][jj] = 0.f;

  int tm = tid >> 4, tn = tid & 15;
  int KT = G / 32;
  for(int kt = 0; kt < KT; kt++){
    int k = kt*32 + lk;
    *(float4*)&Ws[lk][l4]      = *(const float4*)(wb + (size_t)k * F);
    *(float4*)&Ws[lk+16][l4]   = *(const float4*)(wb + (size_t)(k+16) * F);
    *(float4*)&Xs[lk][l4]      = *(const float4*)(Xb + (size_t)k * 512 + n0 + l4);
    *(float4*)&Xs[lk+16][l4]   = *(const float4*)(Xb + (size_t)(k+16) * 512 + n0 + l4);
    __syncthreads();
    #pragma unroll
    for(int kk = 0; kk < 32; kk++){
      float4 a  = *(const float4*)&Ws[kk][tm*4];
      float4 xx = *(const float4*)&Xs[kk][tn*4];
      float av[4]  = {a.x, a.y, a.z, a.w};
      float xvv[4] = {xx.x, xx.y, xx.z, xx.w};
      #pragma unroll
      for(int i = 0; i < 4; i++)
        #pragma unroll
        for(int jj = 0; jj < 4; jj++)
          acc[i][jj] = fmaf(av[i], xvv[jj], acc[i][jj]);
    }
    __syncthreads();
  }

  int F2 = 2*F;
  float* ob = kqT + (size_t)bp * 512 * F2;
  #pragma unroll
  for(int jj = 0; jj < 4; jj++){
    float* orow = ob + (size_t)(n0 + tn*4 + jj) * F2 + m0 + tm*4;
    #pragma unroll
    for(int i = 0; i < 4; i++) orow[i] = acc[i][jj];
  }
}

// ---------------------------------------------------------------------------
// key/qry GEMM, BK=64 variant for 2F=64 (grid 256 blocks = 1/CU: halved
// barrier count matters there). Chain per output identical (K-tiling only).
// ---------------------------------------------------------------------------
__global__ __launch_bounds__(256) void gemm_kqK64(
    const float* __restrict__ X,
    const float* __restrict__ wk, const float* __restrict__ wq,
    float* __restrict__ kqT, int G, int F)
{
  __shared__ float Ws[64][68];
  __shared__ float Xs[64][68];
  int tid = threadIdx.x;
  int bp = blockIdx.z;
  int b = bp >> 2, p = bp & 3;
  int n0 = blockIdx.x * 64, m0 = blockIdx.y * 64;
  const float* Xb = X + (size_t)b * G * 512;

  int lk = tid >> 4;
  int l4 = (tid & 15) * 4;

  int mg = m0 + l4;
  int quad = mg / F;
  int mq = mg - quad * F;
  size_t GF = (size_t)G * F;
  const float* wb = (quad == 0 ? wk : wq) + (size_t)p * GF + mq;

  float acc[4][4];
  #pragma unroll
  for(int i = 0; i < 4; i++)
    #pragma unroll
    for(int jj = 0; jj < 4; jj++) acc[i][jj] = 0.f;

  int tm = tid >> 4, tn = tid & 15;
  int KT = G / 64;
  for(int kt = 0; kt < KT; kt++){
    #pragma unroll
    for(int kb = 0; kb < 4; kb++){
      int k = kt*64 + lk + kb*16;
      *(float4*)&Ws[lk + kb*16][l4] = *(const float4*)(wb + (size_t)k * F);
      *(float4*)&Xs[lk + kb*16][l4] = *(const float4*)(Xb + (size_t)k * 512 + n0 + l4);
    }
    __syncthreads();
    #pragma unroll
    for(int kk = 0; kk < 64; kk++){
      float4 a  = *(const float4*)&Ws[kk][tm*4];
      float4 xx = *(const float4*)&Xs[kk][tn*4];
      float av[4]  = {a.x, a.y, a.z, a.w};
      float xvv[4] = {xx.x, xx.y, xx.z, xx.w};
      #pragma unroll
      for(int i = 0; i < 4; i++)
        #pragma unroll
        for(int jj = 0; jj < 4; jj++)
          acc[i][jj] = fmaf(av[i], xvv[jj], acc[i][jj]);
    }
    __syncthreads();
  }

  int F2 = 2*F;
  float* ob = kqT + (size_t)bp * 512 * F2;
  #pragma unroll
  for(int jj = 0; jj < 4; jj++){
    float* orow = ob + (size_t)(n0 + tn*4 + jj) * F2 + m0 + tm*4;
    #pragma unroll
    for(int i = 0; i < 4; i++) orow[i] = acc[i][jj];
  }
}

// ---------------------------------------------------------------------------
// Sparse scores + masked softmax, item-parallel: block = (16-row n-tile, bp),
// 16 threads per row handle neighbor items (j = t, t+16, ...) -> ~69% active
// lanes vs 17% in the one-wave-per-row version. Softmax reductions stay
// sequential ascending-j (thread t=0 per row) == np order; aij = expf(sc-mx)
// / ssum with bit-identical inputs -> bit-identical output.
// grid: (32 n-tiles, 32 bp) x 256.
// ---------------------------------------------------------------------------
__global__ __launch_bounds__(256) void attn_sparse(
    const float* __restrict__ kqT,
    const int* __restrict__ nbr_idx, const int* __restrict__ nbr_cnt,
    float* __restrict__ aijv, int F, int s)
{
  __shared__ float qs[16][132];
  __shared__ float sc[16][CAP];
  __shared__ float red[16][2];
  int tid = threadIdx.x;
  int n0 = blockIdx.x * 16;
  int bp = blockIdx.y;
  int b = bp >> 2;
  int F2 = 2*F;

  int F4 = F >> 2;
  for(int i = tid; i < 16*F4; i += 256){
    int r = i / F4, c4 = (i - r*F4) * 4;
    *(float4*)&qs[r][c4] =
      *(const float4*)&kqT[((size_t)bp*512 + n0 + r)*F2 + F + c4];
  }
  __syncthreads();

  int r = tid >> 4;         // 0..15 (row)
  int t = tid & 15;         // 0..15 (item lane)
  int n = n0 + r;
  int srow = (b*2 + s)*512 + n;
  int cnt = nbr_cnt[srow];
  const int* il = nbr_idx + (size_t)srow * CAP;

  for(int j = t; j < cnt; j += 16){
    int m = il[j];
    const float* krow = kqT + ((size_t)bp*512 + m)*F2;   // key half
    float a = 0.f;
    for(int f = 0; f < F; f += 4){
      float4 k4 = *(const float4*)&krow[f];
      a = fmaf(qs[r][f],   k4.x, a);
      a = fmaf(qs[r][f+1], k4.y, a);
      a = fmaf(qs[r][f+2], k4.z, a);
      a = fmaf(qs[r][f+3], k4.w, a);
    }
    sc[r][j] = a >= 0.f ? a : 0.2f * a;    // leaky_relu slope 0.2
  }
  __syncthreads();

  if(t == 0){
    float mx = -1e30f;
    for(int j = 0; j < cnt; j++) mx = fmaxf(mx, sc[r][j]);
    float ssum = 0.f;
    for(int j = 0; j < cnt; j++) ssum += expf(sc[r][j] - mx);
    red[r][0] = mx; red[r][1] = ssum;
  }
  __syncthreads();

  float mx = red[r][0], ssum = red[r][1];
  float* arow = aijv + ((size_t)bp*512 + n)*CAP;
  for(int j = t; j < cnt; j += 16)
    arow[j] = expf(sc[r][j] - mx) / ssum;
}

// ---------------------------------------------------------------------------
// Xp[bp][g][n] = sum_j aij[n,j] x[b,g,il[n,j]] (ascending j == np order).
// Grid (8 n-tiles, G/32 g-blocks, 32 bp).
// ---------------------------------------------------------------------------
__global__ __launch_bounds__(256) void fill_Xp(
    const float* __restrict__ X, const float* __restrict__ aijv,
    const int* __restrict__ nbr_idx, const int* __restrict__ nbr_cnt,
    float* __restrict__ Xp, int G, int s)
{
  __shared__ float xrows[8][512];
  __shared__ float av_s[64][CAP+1];
  __shared__ u16   il_s[64][CAP+2];
  __shared__ int   cnt_s[64];

  int tid = threadIdx.x;
  int n0 = blockIdx.x * 64;
  int g0 = blockIdx.y * 32;
  int bp = blockIdx.z;
  int b = bp >> 2;
  int srow0 = (b*2 + s)*512 + n0;

  for(int i = tid; i < 64*CAP; i += 256){
    int r = i / CAP, j = i - r*CAP;
    il_s[r][j] = (u16)nbr_idx[(size_t)(srow0 + r)*CAP + j];
    av_s[r][j] = aijv[((size_t)bp*512 + n0 + r)*CAP + j];
  }
  if(tid < 64) cnt_s[tid] = nbr_cnt[srow0 + tid];

  int n_l = tid & 63;
  int gs  = tid >> 6;
  const float* Xb  = X  + ((size_t)b  * G + g0) * 512;
  float*       XpB = Xp + ((size_t)bp * G + g0) * 512;

  for(int gb = 0; gb < 32; gb += 8){
    __syncthreads();
    for(int i = tid; i < 8*128; i += 256){
      int gr = i >> 7, c4 = (i & 127) * 4;
      *(float4*)&xrows[gr][c4] = *(const float4*)&Xb[(size_t)(gb + gr)*512 + c4];
    }
    __syncthreads();
    int cnt = cnt_s[n_l];
    float a0 = 0.f, a1 = 0.f;
    for(int j = 0; j < cnt; j++){
      float w = av_s[n_l][j];
      int   m = il_s[n_l][j];
      a0 = fmaf(w, xrows[gs][m],     a0);
      a1 = fmaf(w, xrows[gs + 4][m], a1);
    }
    XpB[(size_t)(gb + gs)*512     + n0 + n_l] = a0;
    XpB[(size_t)(gb + gs + 4)*512 + n0 + n_l] = a1;
  }
}

// ---------------------------------------------------------------------------
// Output GEMM 64m x 64n x 32k: y[f,n] = sum_c src(c)[n]*wf[..]; src: X | Xp.
// Padded LDS. Ascending-c chain; +bias, relu, store/accumulate.
// grid (8, ceil(F/64), 32 bp).
// ---------------------------------------------------------------------------
__global__ __launch_bounds__(256) void gemm_y(
    const float* __restrict__ X, const float* __restrict__ Xp,
    const float* __restrict__ wf, const float* __restrict__ bias,
    float* __restrict__ out, int G, int F, int PFout, int accmode)
{
  __shared__ float Ws[32][68];
  __shared__ float Xs[32][68];
  int tid = threadIdx.x;
  int bp = blockIdx.z;
  int b = bp >> 2, p = bp & 3;
  int n0 = blockIdx.x * 64, m0 = blockIdx.y * 64;

  int lk = tid >> 4;
  int l4 = (tid & 15) * 4;
  int mg = m0 + l4;
  int fcl = mg < F ? mg : (F - 4);
  size_t GF2 = (size_t)2 * G * F;
  const float* wb = wf + (size_t)p * GF2 + fcl;

  float acc[4][4];
  #pragma unroll
  for(int i = 0; i < 4; i++)
    #pragma unroll
    for(int jj = 0; jj < 4; jj++) acc[i][jj] = 0.f;

  int tm = tid >> 4, tn = tid & 15;
  int KT = (2*G) / 32;
  for(int kt = 0; kt < KT; kt++){
    int c0 = kt*32 + lk;
    int c1 = c0 + 16;
    const float* xr0 = (c0 < G) ? (X  + ((size_t)b  * G + c0      ) * 512)
                                : (Xp + ((size_t)bp * G + (c0 - G)) * 512);
    const float* xr1 = (c1 < G) ? (X  + ((size_t)b  * G + c1      ) * 512)
                                : (Xp + ((size_t)bp * G + (c1 - G)) * 512);
    *(float4*)&Ws[lk][l4]    = *(const float4*)(wb + (size_t)c0 * F);
    *(float4*)&Ws[lk+16][l4] = *(const float4*)(wb + (size_t)c1 * F);
    *(float4*)&Xs[lk][l4]    = *(const float4*)(xr0 + n0 + l4);
    *(float4*)&Xs[lk+16][l4] = *(const float4*)(xr1 + n0 + l4);
    __syncthreads();
    #pragma unroll
    for(int kk = 0; kk < 32; kk++){
      float4 a  = *(const float4*)&Ws[kk][tm*4];
      float4 xx = *(const float4*)&Xs[kk][tn*4];
      float av[4]  = {a.x, a.y, a.z, a.w};
      float xvv[4] = {xx.x, xx.y, xx.z, xx.w};
      #pragma unroll
      for(int i = 0; i < 4; i++)
        #pragma unroll
        for(int jj = 0; jj < 4; jj++)
          acc[i][jj] = fmaf(av[i], xvv[jj], acc[i][jj]);
    }
    __syncthreads();
  }

  int mrow = m0 + tm*4;
  if(mrow < F){
    float* ob = out + ((size_t)b * PFout + (size_t)p * F + mrow) * 512 + n0 + tn*4;
    #pragma unroll
    for(int i = 0; i < 4; i++){
      float bv = bias[mrow + i];
      float4 r = make_float4(fmaxf(acc[i][0] + bv, 0.f),
                             fmaxf(acc[i][1] + bv, 0.f),
                             fmaxf(acc[i][2] + bv, 0.f),
                             fmaxf(acc[i][3] + bv, 0.f));
      float* dst = ob + (size_t)i * 512;
      if(accmode){
        float4 old = *(float4*)dst;
        r.x += old.x; r.y += old.y; r.z += old.z; r.w += old.w;
      }
      *(float4*)dst = r;
    }
  }
}

// ---------------------------------------------------------------------------
// Output GEMM, BK=64 variant for F <= 64 (grid 256 blocks = 1/CU).
// ---------------------------------------------------------------------------
__global__ __launch_bounds__(256) void gemm_yK64(
    const float* __restrict__ X, const float* __restrict__ Xp,
    const float* __restrict__ wf, const float* __restrict__ bias,
    float* __restrict__ out, int G, int F, int PFout, int accmode)
{
  __shared__ float Ws[64][68];
  __shared__ float Xs[64][68];
  int tid = threadIdx.x;
  int bp = blockIdx.z;
  int b = bp >> 2, p = bp & 3;
  int n0 = blockIdx.x * 64, m0 = blockIdx.y * 64;

  int lk = tid >> 4;
  int l4 = (tid & 15) * 4;
  int mg = m0 + l4;
  int fcl = mg < F ? mg : (F - 4);
  size_t GF2 = (size_t)2 * G * F;
  const float* wb = wf + (size_t)p * GF2 + fcl;

  float acc[4][4];
  #pragma unroll
  for(int i = 0; i < 4; i++)
    #pragma unroll
    for(int jj = 0; jj < 4; jj++) acc[i][jj] = 0.f;

  int tm = tid >> 4, tn = tid & 15;
  int KT = (2*G) / 64;
  for(int kt = 0; kt < KT; kt++){
    #pragma unroll
    for(int kb = 0; kb < 4; kb++){
      int c = kt*64 + lk + kb*16;
      const float* xr = (c < G) ? (X  + ((size_t)b  * G + c      ) * 512)
                                : (Xp + ((size_t)bp * G + (c - G)) * 512);
      *(float4*)&Ws[lk + kb*16][l4] = *(const float4*)(wb + (size_t)c * F);
      *(float4*)&Xs[lk + kb*16][l4] = *(const float4*)(xr + n0 + l4);
    }
    __syncthreads();
    #pragma unroll
    for(int kk = 0; kk < 64; kk++){
      float4 a  = *(const float4*)&Ws[kk][tm*4];
      float4 xx = *(const float4*)&Xs[kk][tn*4];
      float av[4]  = {a.x, a.y, a.z, a.w};
      float xvv[4] = {xx.x, xx.y, xx.z, xx.w};
      #pragma unroll
      for(int i = 0; i < 4; i++)
        #pragma unroll
        for(int jj = 0; jj < 4; jj++)
          acc[i][jj] = fmaf(av[i], xvv[jj], acc[i][jj]);
    }
    __syncthreads();
  }

  int mrow = m0 + tm*4;
  if(mrow < F){
    float* ob = out + ((size_t)b * PFout + (size_t)p * F + mrow) * 512 + n0 + tn*4;
    #pragma unroll
    for(int i = 0; i < 4; i++){
      float bv = bias[mrow + i];
      float4 r = make_float4(fmaxf(acc[i][0] + bv, 0.f),
                             fmaxf(acc[i][1] + bv, 0.f),
                             fmaxf(acc[i][2] + bv, 0.f),
                             fmaxf(acc[i][3] + bv, 0.f));
      float* dst = ob + (size_t)i * 512;
      if(accmode){
        float4 old = *(float4*)dst;
        r.x += old.x; r.y += old.y; r.z += old.z; r.w += old.w;
      }
      *(float4*)dst = r;
    }
  }
}

// ---------------------------------------------------------------------------
// dec0 GEMM: d[row][m] = relu( sum_{c<512} u1flat[row][c]*dw0T[c][m] + b0[m] );
// u1flat row r is contiguous memory at u1 + r*512. Tile 64x64x16, padded LDS.
// grid (64, 4).
// ---------------------------------------------------------------------------
__global__ __launch_bounds__(256) void gemm_dec0(
    const float* __restrict__ u1, const float* __restrict__ w0T,
    const float* __restrict__ b0, float* __restrict__ d)
{
  __shared__ float As[16][68];
  __shared__ float Bs[16][68];
  int tid = threadIdx.x;
  int n0 = blockIdx.x * 64;
  int m0 = blockIdx.y * 64;

  int lk = tid >> 4;
  int l4 = (tid & 15) * 4;
  int br = tid >> 2;
  int bc = (tid & 3) * 4;

  float acc[4][4];
  #pragma unroll
  for(int i = 0; i < 4; i++)
    #pragma unroll
    for(int jj = 0; jj < 4; jj++) acc[i][jj] = 0.f;

  int tm = tid >> 4, tn = tid & 15;
  for(int kt = 0; kt < 32; kt++){
    int k0 = kt*16;
    *(float4*)&As[lk][l4] = *(const float4*)&w0T[(size_t)(k0 + lk)*256 + m0 + l4];
    float4 bv = *(const float4*)&u1[(size_t)(n0 + br)*512 + k0 + bc];
    Bs[bc+0][br] = bv.x; Bs[bc+1][br] = bv.y; Bs[bc+2][br] = bv.z; Bs[bc+3][br] = bv.w;
    __syncthreads();
    #pragma unroll
    for(int kk = 0; kk < 16; kk++){
      float4 a  = *(const float4*)&As[kk][tm*4];
      float4 xx = *(const float4*)&Bs[kk][tn*4];
      float av[4]  = {a.x, a.y, a.z, a.w};
      float xvv[4] = {xx.x, xx.y, xx.z, xx.w};
      #pragma unroll
      for(int i = 0; i < 4; i++)
        #pragma unroll
        for(int jj = 0; jj < 4; jj++)
          acc[i][jj] = fmaf(av[i], xvv[jj], acc[i][jj]);
    }
    __syncthreads();
  }

  #pragma unroll
  for(int jj = 0; jj < 4; jj++){
    int row = n0 + tn*4 + jj;
    float4 r = make_float4(fmaxf(acc[0][jj] + b0[m0+tm*4+0], 0.f),
                           fmaxf(acc[1][jj] + b0[m0+tm*4+1], 0.f),
                           fmaxf(acc[2][jj] + b0[m0+tm*4+2], 0.f),
                           fmaxf(acc[3][jj] + b0[m0+tm*4+3], 0.f));
    *(float4*)&d[(size_t)row*256 + m0 + tm*4] = r;
  }
}

// ---------------------------------------------------------------------------
// Decoder stage 2: one wave per row; 5 sequential np-order dots + softmax.
// ---------------------------------------------------------------------------
__global__ __launch_bounds__(64) void decoder2(
    const float* __restrict__ d,
    const float* __restrict__ w1, const float* __restrict__ b1,
    const int* __restrict__ flag, void* __restrict__ outp)
{
  __shared__ float ds[256];
  __shared__ float lg[5];
  int r = blockIdx.x, lane = threadIdx.x;
  for(int i = lane; i < 256; i += 64) ds[i] = d[(size_t)r*256 + i];
  __syncthreads();

  if(lane < 5){
    float a = 0.f;
    const float* wr = w1 + (size_t)lane * 256;
    for(int i = 0; i < 256; i++) a = fmaf(ds[i], wr[i], a);
    lg[lane] = a + b1[lane];
  }
  __syncthreads();
  if(lane < 5){
    float mx = lg[0];
    for(int i = 1; i < 5; i++) mx = fmaxf(mx, lg[i]);
    float ssum = 0.f;
    for(int i = 0; i < 5; i++) ssum += expf(lg[i] - mx);
    float v = expf(lg[lane] - mx) / ssum;
    if(*flag) ((float*)outp)[(size_t)r*5 + lane] = v;
    else      ((u16*)outp)[(size_t)r*5 + lane] = fromf(v);
  }
}

// ---------------------------------------------------------------------------
extern "C" void kernel_launch(void* const* d_in, const int* in_sizes, int n_in,
                              void* d_out, int out_size, void* d_ws, size_t ws_size,
                              hipStream_t stream)
{
  (void)n_in; (void)out_size; (void)ws_size;
  const void* x = d_in[0];
  const void* S = d_in[1];

  float* wsf   = (float*)d_ws;
  int*   flag  = (int*)d_ws;          // word 0
  float* arena = wsf + 1024;

  WArgs wa;
  long long aoff[35]; aoff[0] = 0;
  for(int t = 0; t < 34; t++){
    wa.p[t]  = d_in[2 + t];
    wa.sz[t] = in_sizes[2 + t];
    wa.off[t] = (int)aoff[t];
    aoff[t+1] = aoff[t] + ((in_sizes[2 + t] + 15) & ~15);
  }
  wa.off[34] = (int)aoff[34];
  int total = (int)aoff[34];

  size_t cur = 1024 + (size_t)((total + 1023) & ~1023);
  float* g    = wsf + cur; cur += 524288;                 // (B,128,512) flat
  float* p1   = wsf + cur; cur += 2097152;                // (B,512,512)
  float* p2   = wsf + cur; cur += 524288;                 // (B,128,512)
  float* u0b  = wsf + cur; cur += 1048576;                // (B,256,512)
  float* u1b  = p1;                                       // reuse (p1 dead after L3 reads)
  float* scr  = wsf + cur; cur += (size_t)32*512*512;     // e1 / kqT / Xp / d union
  float* aijv = wsf + cur; cur += (size_t)32*512*CAP;     // (32, 512, CAP)
  float* fwT  = wsf + cur; cur += 98304;                  // (768,128)
  float* dw0T = wsf + cur; cur += 131072;                 // (512,256)
  int*   ncnt = (int*)(wsf + cur); cur += 8192;
  int*   nidx = (int*)(wsf + cur); cur += (size_t)8192 * CAP;

  float* e1n = scr;   // [4096][768]   — dead after gemm_flat
  float* kqT = scr;   // [32][512][2F] — dead after attn_sparse
  float* Xp  = scr;   // [32][G][512]  — written after attn_sparse
  float* dbuf= scr;   // [4096][256]   — after layers

  const float* A[34];
  for(int t = 0; t < 34; t++) A[t] = arena + aoff[t];
  const float* c0w = A[0], *c0b = A[1], *c1w = A[2], *c1b = A[3];
  const float* fw  = A[4], *fb  = A[5];
  const float *wk_[6], *wq_[6], *wf_[6], *bias_[6];
  for(int l = 0; l < 6; l++){
    wk_[l]   = A[6 + 4*l];
    wq_[l]   = A[7 + 4*l];
    wf_[l]   = A[8 + 4*l];
    bias_[l] = A[9 + 4*l];
  }
  const float* dw0 = A[30], *db0 = A[31], *dw1 = A[32], *db1 = A[33];

  detect_dtype<<<1, 64, 0, stream>>>(x, flag);
  convert_weights<<<(total + 255)/256, 256, 0, stream>>>(wa, flag, arena, total);
  transpose_w<<<(98304 + 255)/256, 256, 0, stream>>>(fw, fwT, 128, 768);
  transpose_w<<<(131072 + 255)/256, 256, 0, stream>>>(dw0, dw0T, 256, 512);
  build_nbr<<<8192, 64, 0, stream>>>(S, nidx, ncnt, flag);
  encoder_conv<<<4096, 256, 0, stream>>>(x, flag, c0w, c0b, c1w, c1b, e1n);
  gemm_flat<<<dim3(64, 2), 256, 0, stream>>>(e1n, fwT, fb, g);

  struct Lyr { int G, F, s; const float* in; float* out; int PF; int acc; int w; };
  const Lyr Ls[6] = {
    {128, 128, 0, g,   p1,  512, 0, 0},  // p1 = gat(g, S0, d0)
    {512,  32, 1, p1,  p2,  128, 0, 1},  // p2 = gat(p1, S1, d1)
    {128,  64, 1, p2,  u0b, 256, 0, 2},  // u0  = gat(p2, S1, u0)
    {512,  64, 1, p1,  u0b, 256, 1, 5},  //     + gat(p1, S1, s1)
    {256, 128, 0, u0b, u1b, 512, 0, 3},  // u1  = gat(u0, S0, u1)
    {128, 128, 0, g,   u1b, 512, 1, 4},  //     + gat(g,  S0, s0)
  };
  for(int i = 0; i < 6; i++){
    const Lyr& L = Ls[i];
    if(2*L.F <= 64){
      dim3 gk(8, 1, 32);
      gemm_kqK64<<<gk, 256, 0, stream>>>(L.in, wk_[L.w], wq_[L.w], kqT, L.G, L.F);
    } else {
      dim3 gk(8, (2*L.F)/64, 32);
      gemm_kq<<<gk, 256, 0, stream>>>(L.in, wk_[L.w], wq_[L.w], kqT, L.G, L.F);
    }
    attn_sparse<<<dim3(32, 32), 256, 0, stream>>>(kqT, nidx, ncnt, aijv, L.F, L.s);
    fill_Xp<<<dim3(8, L.G/32, 32), 256, 0, stream>>>(L.in, aijv, nidx, ncnt, Xp, L.G, L.s);
    if(L.F <= 64){
      dim3 gy(8, 1, 32);
      gemm_yK64<<<gy, 256, 0, stream>>>(L.in, Xp, wf_[L.w], bias_[L.w], L.out,
                                        L.G, L.F, L.PF, L.acc);
    } else {
      dim3 gy(8, (L.F + 63)/64, 32);
      gemm_y<<<gy, 256, 0, stream>>>(L.in, Xp, wf_[L.w], bias_[L.w], L.out,
                                     L.G, L.F, L.PF, L.acc);
    }
  }

  gemm_dec0<<<dim3(64, 4), 256, 0, stream>>>(u1b, dw0T, db0, dbuf);
  decoder2<<<4096, 64, 0, stream>>>(dbuf, dw1, db1, flag, d_out);
}